// Round 1
// baseline (349.484 us; speedup 1.0000x reference)
//
#include <hip/hip_runtime.h>

#define NN 100000
#define NE 3200000
#define CC 256
#define NEG_SLOPE 0.2f
#define NCOPY 8   // XCD-striped partial copies for the scatter-add

typedef __attribute__((ext_vector_type(8))) _Float16 half8;

// Kernel Z: zero the 8 partial copies (3.2 MB).
__global__ __launch_bounds__(256) void zero_kernel(float4* __restrict__ p, int n4) {
  int i = blockIdx.x * blockDim.x + threadIdx.x;
  if (i < n4) p[i] = make_float4(0.f, 0.f, 0.f, 0.f);
}

// Kernel A: dual dot product, 16 lanes per node (4 nodes/wave).
// Lane gl loads x[node][16gl .. 16gl+15] (4 consecutive float4 = 64 B/lane,
// contiguous 1 KB per 16-lane group). Reduce = 4 shfl_xor steps (vs 6 before,
// and 3x fewer cross-lane ops per node, 4x fewer waves).
__global__ __launch_bounds__(256) void node_scores_kernel(
    const float* __restrict__ x,
    const float* __restrict__ att,
    float* __restrict__ s_src,
    float* __restrict__ s_dst) {
  int t   = blockIdx.x * blockDim.x + threadIdx.x;
  int node = t >> 4;
  int gl   = t & 15;
  if (node >= NN) return;
  const float4* xr = (const float4*)(x + (size_t)node * CC) + gl * 4;
  const float4* a0 = (const float4*)att + gl * 4;         // att[:C]
  const float4* a1 = (const float4*)(att + CC) + gl * 4;  // att[C:]
  float s0 = 0.f, s1 = 0.f;
#pragma unroll
  for (int j = 0; j < 4; ++j) {
    float4 xv = xr[j];
    float4 av = a0[j];
    float4 bv = a1[j];
    s0 += xv.x * av.x + xv.y * av.y + xv.z * av.z + xv.w * av.w;
    s1 += xv.x * bv.x + xv.y * bv.y + xv.z * bv.z + xv.w * bv.w;
  }
#pragma unroll
  for (int m = 8; m >= 1; m >>= 1) {
    s0 += __shfl_xor(s0, m, 64);  // masks <16 stay within the 16-lane group
    s1 += __shfl_xor(s1, m, 64);
  }
  if (gl == 0) {
    s_src[node] = s0;
    s_dst[node] = s1;
  }
}

// Kernel B': 8 edges/thread: score -> leaky_relu -> exp -> store e as fp16,
// AND scatter-add e into an XCD-striped fp32 partial (fire-and-forget
// global_atomic_add_f32; device-scope => correct regardless of dispatch
// mapping, bid%8 striping is an L2-locality heuristic).
// Accumulates the f16-ROUNDED value to match the normalization in kernel E.
__global__ __launch_bounds__(256) void edge_exp_kernel(
    const int4* __restrict__ row4,
    const int4* __restrict__ col4,
    const float* __restrict__ s_src,
    const float* __restrict__ s_dst,
    half8* __restrict__ e_out,
    float* __restrict__ partial /* [NCOPY][NN] */) {
  int i = blockIdx.x * blockDim.x + threadIdx.x;
  if (i >= NE / 8) return;
  float* part = partial + (size_t)(blockIdx.x & (NCOPY - 1)) * NN;
  int4 ra = row4[2 * i], rb = row4[2 * i + 1];
  int4 ca = col4[2 * i], cb = col4[2 * i + 1];
  float a0 = s_src[ra.x] + s_dst[ca.x];
  float a1 = s_src[ra.y] + s_dst[ca.y];
  float a2 = s_src[ra.z] + s_dst[ca.z];
  float a3 = s_src[ra.w] + s_dst[ca.w];
  float a4 = s_src[rb.x] + s_dst[cb.x];
  float a5 = s_src[rb.y] + s_dst[cb.y];
  float a6 = s_src[rb.z] + s_dst[cb.z];
  float a7 = s_src[rb.w] + s_dst[cb.w];
  a0 = (a0 > 0.0f) ? a0 : NEG_SLOPE * a0;
  a1 = (a1 > 0.0f) ? a1 : NEG_SLOPE * a1;
  a2 = (a2 > 0.0f) ? a2 : NEG_SLOPE * a2;
  a3 = (a3 > 0.0f) ? a3 : NEG_SLOPE * a3;
  a4 = (a4 > 0.0f) ? a4 : NEG_SLOPE * a4;
  a5 = (a5 > 0.0f) ? a5 : NEG_SLOPE * a5;
  a6 = (a6 > 0.0f) ? a6 : NEG_SLOPE * a6;
  a7 = (a7 > 0.0f) ? a7 : NEG_SLOPE * a7;
  half8 h;
  h[0] = (_Float16)__expf(a0);
  h[1] = (_Float16)__expf(a1);
  h[2] = (_Float16)__expf(a2);
  h[3] = (_Float16)__expf(a3);
  h[4] = (_Float16)__expf(a4);
  h[5] = (_Float16)__expf(a5);
  h[6] = (_Float16)__expf(a6);
  h[7] = (_Float16)__expf(a7);
  e_out[i] = h;
  atomicAdd(&part[ra.x], (float)h[0]);
  atomicAdd(&part[ra.y], (float)h[1]);
  atomicAdd(&part[ra.z], (float)h[2]);
  atomicAdd(&part[ra.w], (float)h[3]);
  atomicAdd(&part[rb.x], (float)h[4]);
  atomicAdd(&part[rb.y], (float)h[5]);
  atomicAdd(&part[rb.z], (float)h[6]);
  atomicAdd(&part[rb.w], (float)h[7]);
}

// Kernel D': fold the 8 copies, store reciprocal. 3.2 MB read -> ~2 us.
__global__ __launch_bounds__(256) void reduce_kernel(
    const float* __restrict__ partial,
    float* __restrict__ denom) {
  int n = blockIdx.x * blockDim.x + threadIdx.x;
  if (n >= NN) return;
  float s = 0.f;
#pragma unroll
  for (int c = 0; c < NCOPY; ++c) s += partial[(size_t)c * NN + n];
  denom[n] = 1.f / s;
}

// Kernel E: 8 edges/thread, normalize e (fp16) into final fp32 out.
__global__ __launch_bounds__(256) void edge_div_kernel(
    const int4* __restrict__ row4,
    const half8* __restrict__ e,
    const float* __restrict__ denom,
    float4* __restrict__ out4) {
  int i = blockIdx.x * blockDim.x + threadIdx.x;
  if (i >= NE / 8) return;
  int4 ra = row4[2 * i], rb = row4[2 * i + 1];
  half8 ev = e[i];
  float4 oa, ob;
  oa.x = (float)ev[0] * denom[ra.x];
  oa.y = (float)ev[1] * denom[ra.y];
  oa.z = (float)ev[2] * denom[ra.z];
  oa.w = (float)ev[3] * denom[ra.w];
  ob.x = (float)ev[4] * denom[rb.x];
  ob.y = (float)ev[5] * denom[rb.y];
  ob.z = (float)ev[6] * denom[rb.z];
  ob.w = (float)ev[7] * denom[rb.w];
  out4[2 * i]     = oa;
  out4[2 * i + 1] = ob;
}

extern "C" void kernel_launch(void* const* d_in, const int* in_sizes, int n_in,
                              void* d_out, int out_size, void* d_ws, size_t ws_size,
                              hipStream_t stream) {
  const float* x   = (const float*)d_in[0];
  const float* att = (const float*)d_in[1];
  const int* ei    = (const int*)d_in[2];  // (2, E): row then col (int32)
  const int4* row4 = (const int4*)ei;
  const int4* col4 = (const int4*)(ei + NE);
  float4* out4     = (float4*)d_out;  // E floats, final output

  float* s_src    = (float*)d_ws;            // N f32
  float* s_dst    = s_src + NN;              // N f32
  float* denom    = s_dst + NN;              // N f32
  _Float16* e_buf = (_Float16*)(denom + NN); // E f16 (6.4 MB)
  float* partial  = (float*)(e_buf + NE);    // NCOPY * N f32 (3.2 MB)

  zero_kernel<<<(NCOPY * NN / 4 + 255) / 256, 256, 0, stream>>>(
      (float4*)partial, NCOPY * NN / 4);
  node_scores_kernel<<<(NN * 16 + 255) / 256, 256, 0, stream>>>(x, att, s_src, s_dst);
  edge_exp_kernel<<<(NE / 8 + 255) / 256, 256, 0, stream>>>(
      row4, col4, s_src, s_dst, (half8*)e_buf, partial);
  reduce_kernel<<<(NN + 255) / 256, 256, 0, stream>>>(partial, denom);
  edge_div_kernel<<<(NE / 8 + 255) / 256, 256, 0, stream>>>(
      row4, (const half8*)e_buf, denom, out4);
}

// Round 2
// 239.389 us; speedup vs baseline: 1.4599x; 1.4599x over previous
//
#include <hip/hip_runtime.h>

#define NN 100000
#define NE 3200000
#define CC 256
#define NEG_SLOPE 0.2f

#define SEG_S 64       // edge slices (non-atomic partials)
#define SEG_P 4        // node partitions (was 8): 100 KB LDS per block
#define PART_SZ 25000  // NN / SEG_P -> 100 KB LDS (gfx950 allows up to 160 KB/wg)
#define SEG_BLOCK 1024
#define ESLICE (NE / SEG_S)  // 50000 edges per slice

typedef __attribute__((ext_vector_type(8))) _Float16 half8;

// Kernel A: dual dot product, 16 lanes per node (4 nodes/wave).
// Lane gl loads x[node][16gl .. 16gl+15] (4 consecutive float4 = 64 B/lane).
// Reduce = 4 shfl_xor steps within the 16-lane group.
__global__ __launch_bounds__(256) void node_scores_kernel(
    const float* __restrict__ x,
    const float* __restrict__ att,
    float* __restrict__ s_src,
    float* __restrict__ s_dst) {
  int t    = blockIdx.x * blockDim.x + threadIdx.x;
  int node = t >> 4;
  int gl   = t & 15;
  if (node >= NN) return;
  const float4* xr = (const float4*)(x + (size_t)node * CC) + gl * 4;
  const float4* a0 = (const float4*)att + gl * 4;         // att[:C]
  const float4* a1 = (const float4*)(att + CC) + gl * 4;  // att[C:]
  float s0 = 0.f, s1 = 0.f;
#pragma unroll
  for (int j = 0; j < 4; ++j) {
    float4 xv = xr[j];
    float4 av = a0[j];
    float4 bv = a1[j];
    s0 += xv.x * av.x + xv.y * av.y + xv.z * av.z + xv.w * av.w;
    s1 += xv.x * bv.x + xv.y * bv.y + xv.z * bv.z + xv.w * bv.w;
  }
#pragma unroll
  for (int m = 8; m >= 1; m >>= 1) {
    s0 += __shfl_xor(s0, m, 64);  // masks <16 stay within the 16-lane group
    s1 += __shfl_xor(s1, m, 64);
  }
  if (gl == 0) {
    s_src[node] = s0;
    s_dst[node] = s1;
  }
}

// Kernel B: 8 edges/thread: score -> leaky_relu -> exp -> store e as fp16.
// exp(alpha) in [e^-2, e^8]: fp16 rel err 5e-4, safe vs 1.55e-2 threshold.
// Max-subtraction of softmax cancels algebraically, so no segment-max pass.
__global__ __launch_bounds__(256) void edge_exp_kernel(
    const int4* __restrict__ row4,
    const int4* __restrict__ col4,
    const float* __restrict__ s_src,
    const float* __restrict__ s_dst,
    half8* __restrict__ e_out) {
  int i = blockIdx.x * blockDim.x + threadIdx.x;
  if (i >= NE / 8) return;
  int4 ra = row4[2 * i], rb = row4[2 * i + 1];
  int4 ca = col4[2 * i], cb = col4[2 * i + 1];
  float a0 = s_src[ra.x] + s_dst[ca.x];
  float a1 = s_src[ra.y] + s_dst[ca.y];
  float a2 = s_src[ra.z] + s_dst[ca.z];
  float a3 = s_src[ra.w] + s_dst[ca.w];
  float a4 = s_src[rb.x] + s_dst[cb.x];
  float a5 = s_src[rb.y] + s_dst[cb.y];
  float a6 = s_src[rb.z] + s_dst[cb.z];
  float a7 = s_src[rb.w] + s_dst[cb.w];
  a0 = (a0 > 0.0f) ? a0 : NEG_SLOPE * a0;
  a1 = (a1 > 0.0f) ? a1 : NEG_SLOPE * a1;
  a2 = (a2 > 0.0f) ? a2 : NEG_SLOPE * a2;
  a3 = (a3 > 0.0f) ? a3 : NEG_SLOPE * a3;
  a4 = (a4 > 0.0f) ? a4 : NEG_SLOPE * a4;
  a5 = (a5 > 0.0f) ? a5 : NEG_SLOPE * a5;
  a6 = (a6 > 0.0f) ? a6 : NEG_SLOPE * a6;
  a7 = (a7 > 0.0f) ? a7 : NEG_SLOPE * a7;
  half8 h;
  h[0] = (_Float16)__expf(a0);
  h[1] = (_Float16)__expf(a1);
  h[2] = (_Float16)__expf(a2);
  h[3] = (_Float16)__expf(a3);
  h[4] = (_Float16)__expf(a4);
  h[5] = (_Float16)__expf(a5);
  h[6] = (_Float16)__expf(a6);
  h[7] = (_Float16)__expf(a7);
  e_out[i] = h;
}

// Kernel C: atomic-free segment sum. Block (s,p) streams slice s, LDS-adds
// rows in partition p, writes its tile as a NON-atomic partial.
// Grid (SEG_S, SEG_P) with s fastest: sibling blocks of a slice get
// ids {s, s+64, s+128, s+192} == s (mod 8) -> same XCD under round-robin,
// so the 4x slice re-read hits that XCD's 4 MB L2 (slice = 200KB row +
// 100KB e-f16; 8 slices x 300KB = 2.4 MB per XCD working set).
__global__ __launch_bounds__(SEG_BLOCK) void segsum_kernel(
    const int* __restrict__ row,
    const _Float16* __restrict__ e,
    float* __restrict__ partial /* [SEG_S][NN] */) {
  __shared__ float lds[PART_SZ];  // 100 KB
  int s = blockIdx.x;  // edge slice
  int p = blockIdx.y;  // node partition
  for (int i = threadIdx.x; i < PART_SZ; i += SEG_BLOCK) lds[i] = 0.0f;
  __syncthreads();
  int lo = p * PART_SZ;
  const int4*  row4 = (const int4*)(row + s * ESLICE);
  const half8* e8   = (const half8*)(e + (size_t)s * ESLICE);
  const int n8 = ESLICE / 8;  // 6250
  for (int i = threadIdx.x; i < n8; i += SEG_BLOCK) {
    int4 ra = row4[2 * i], rb = row4[2 * i + 1];
    half8 ev = e8[i];
    int r0 = ra.x - lo; if ((unsigned)r0 < PART_SZ) atomicAdd(&lds[r0], (float)ev[0]);
    int r1 = ra.y - lo; if ((unsigned)r1 < PART_SZ) atomicAdd(&lds[r1], (float)ev[1]);
    int r2 = ra.z - lo; if ((unsigned)r2 < PART_SZ) atomicAdd(&lds[r2], (float)ev[2]);
    int r3 = ra.w - lo; if ((unsigned)r3 < PART_SZ) atomicAdd(&lds[r3], (float)ev[3]);
    int r4 = rb.x - lo; if ((unsigned)r4 < PART_SZ) atomicAdd(&lds[r4], (float)ev[4]);
    int r5 = rb.y - lo; if ((unsigned)r5 < PART_SZ) atomicAdd(&lds[r5], (float)ev[5]);
    int r6 = rb.z - lo; if ((unsigned)r6 < PART_SZ) atomicAdd(&lds[r6], (float)ev[6]);
    int r7 = rb.w - lo; if ((unsigned)r7 < PART_SZ) atomicAdd(&lds[r7], (float)ev[7]);
  }
  __syncthreads();
  float* outp = partial + (size_t)s * NN + lo;
  for (int i = threadIdx.x; i < PART_SZ; i += SEG_BLOCK) outp[i] = lds[i];
}

// Kernel D: fold 64 slice-partials (float4), store reciprocal.
__global__ __launch_bounds__(256) void reduce_kernel(
    const float* __restrict__ partial,
    float* __restrict__ denom) {
  int n4 = blockIdx.x * blockDim.x + threadIdx.x;
  if (n4 >= NN / 4) return;
  float4 sum = make_float4(0.f, 0.f, 0.f, 0.f);
#pragma unroll 8
  for (int s = 0; s < SEG_S; ++s) {
    float4 v = ((const float4*)(partial + (size_t)s * NN))[n4];
    sum.x += v.x; sum.y += v.y; sum.z += v.z; sum.w += v.w;
  }
  ((float4*)denom)[n4] = make_float4(1.f / sum.x, 1.f / sum.y, 1.f / sum.z, 1.f / sum.w);
}

// Kernel E: 8 edges/thread, normalize e (fp16) into final fp32 out.
__global__ __launch_bounds__(256) void edge_div_kernel(
    const int4* __restrict__ row4,
    const half8* __restrict__ e,
    const float* __restrict__ denom,
    float4* __restrict__ out4) {
  int i = blockIdx.x * blockDim.x + threadIdx.x;
  if (i >= NE / 8) return;
  int4 ra = row4[2 * i], rb = row4[2 * i + 1];
  half8 ev = e[i];
  float4 oa, ob;
  oa.x = (float)ev[0] * denom[ra.x];
  oa.y = (float)ev[1] * denom[ra.y];
  oa.z = (float)ev[2] * denom[ra.z];
  oa.w = (float)ev[3] * denom[ra.w];
  ob.x = (float)ev[4] * denom[rb.x];
  ob.y = (float)ev[5] * denom[rb.y];
  ob.z = (float)ev[6] * denom[rb.z];
  ob.w = (float)ev[7] * denom[rb.w];
  out4[2 * i]     = oa;
  out4[2 * i + 1] = ob;
}

extern "C" void kernel_launch(void* const* d_in, const int* in_sizes, int n_in,
                              void* d_out, int out_size, void* d_ws, size_t ws_size,
                              hipStream_t stream) {
  const float* x   = (const float*)d_in[0];
  const float* att = (const float*)d_in[1];
  const int* ei    = (const int*)d_in[2];  // (2, E): row then col (int32)
  const int* row   = ei;
  const int4* row4 = (const int4*)ei;
  const int4* col4 = (const int4*)(ei + NE);
  float4* out4     = (float4*)d_out;  // E floats, final output

  float* s_src    = (float*)d_ws;            // N f32
  float* s_dst    = s_src + NN;              // N f32
  float* denom    = s_dst + NN;              // N f32
  _Float16* e_buf = (_Float16*)(denom + NN); // E f16 (6.4 MB)
  float* partial  = (float*)(e_buf + NE);    // SEG_S * N f32 (25.6 MB)

  node_scores_kernel<<<(NN * 16 + 255) / 256, 256, 0, stream>>>(x, att, s_src, s_dst);
  edge_exp_kernel<<<(NE / 8 + 255) / 256, 256, 0, stream>>>(
      row4, col4, s_src, s_dst, (half8*)e_buf);
  dim3 seg_grid(SEG_S, SEG_P);
  segsum_kernel<<<seg_grid, SEG_BLOCK, 0, stream>>>(row, e_buf, partial);
  reduce_kernel<<<(NN / 4 + 255) / 256, 256, 0, stream>>>(partial, denom);
  edge_div_kernel<<<(NE / 8 + 255) / 256, 256, 0, stream>>>(
      row4, (const half8*)e_buf, denom, out4);
}

// Round 3
// 232.755 us; speedup vs baseline: 1.5015x; 1.0285x over previous
//
#include <hip/hip_runtime.h>

#define NN 100000
#define NE 3200000
#define CC 256
#define NEG_SLOPE 0.2f

// Fused exp+segsum pass: 32 edge slices x 8 node partitions (256 blocks).
#define CS_S 32
#define CS_P 8
#define CS_PART 12500        // NN / CS_P: 50 KB src chunk + 50 KB acc = 100 KB LDS
#define CS_ESL (NE / CS_S)   // 100000 edges per slice

// Normalize pass: 64 slices x 4 partitions (256 blocks), 100 KB denom LDS.
#define EN_S 64
#define EN_P 4
#define EN_PART 25000
#define EN_ESL (NE / EN_S)   // 50000 edges per slice

#define BLK 1024

typedef __attribute__((ext_vector_type(8))) _Float16 half8;

// Kernel A: dual dot product, 16 lanes per node (4 nodes/wave).
// Lane gl loads x[node][16gl .. 16gl+15] (4 consecutive float4 = 64 B/lane).
__global__ __launch_bounds__(256) void node_scores_kernel(
    const float* __restrict__ x,
    const float* __restrict__ att,
    float* __restrict__ s_src,
    float* __restrict__ s_dst) {
  int t    = blockIdx.x * blockDim.x + threadIdx.x;
  int node = t >> 4;
  int gl   = t & 15;
  if (node >= NN) return;
  const float4* xr = (const float4*)(x + (size_t)node * CC) + gl * 4;
  const float4* a0 = (const float4*)att + gl * 4;         // att[:C]
  const float4* a1 = (const float4*)(att + CC) + gl * 4;  // att[C:]
  float s0 = 0.f, s1 = 0.f;
#pragma unroll
  for (int j = 0; j < 4; ++j) {
    float4 xv = xr[j];
    float4 av = a0[j];
    float4 bv = a1[j];
    s0 += xv.x * av.x + xv.y * av.y + xv.z * av.z + xv.w * av.w;
    s1 += xv.x * bv.x + xv.y * bv.y + xv.z * bv.z + xv.w * bv.w;
  }
#pragma unroll
  for (int m = 8; m >= 1; m >>= 1) {
    s0 += __shfl_xor(s0, m, 64);  // masks <16 stay within the 16-lane group
    s1 += __shfl_xor(s1, m, 64);
  }
  if (gl == 0) {
    s_src[node] = s0;
    s_dst[node] = s1;
  }
}

// Kernel C': FUSED exp + segment-sum. Block (s,p) stages s_src partition p in
// LDS, streams slice s's row+col, and for hit lanes only (row in partition):
//   gather s_dst[col] (the ONLY remaining random gather in the pipeline,
//   issued predicated so total requests across the grid = NE, not NE*CS_P),
//   compute leaky+exp, store e (f16, rounded), LDS-accumulate.
// Max-subtraction of softmax cancels algebraically -> no segment-max pass.
// exp(alpha) in [e^-2, e^8]: f16 rel err 5e-4, safe vs 1.55e-2 threshold.
// Grid (CS_S, CS_P): sibling blocks (same s) have linear id == s (mod 8)
// -> same XCD -> slice row/col streams stay in that XCD's L2 across the
// 8 partition passes; sparse e stores merge in the same L2.
__global__ __launch_bounds__(BLK) void fused_segsum_kernel(
    const int* __restrict__ row,
    const int* __restrict__ col,
    const float* __restrict__ s_src,
    const float* __restrict__ s_dst,
    _Float16* __restrict__ e_out,
    float* __restrict__ partial /* [CS_S][NN] */) {
  __shared__ float src_lds[CS_PART];  // 50 KB
  __shared__ float acc[CS_PART];      // 50 KB
  int s  = blockIdx.x;
  int p  = blockIdx.y;
  int lo = p * CS_PART;
  for (int i = threadIdx.x; i < CS_PART; i += BLK) {
    src_lds[i] = s_src[lo + i];
    acc[i]     = 0.0f;
  }
  __syncthreads();
  const int4* row4 = (const int4*)(row + s * CS_ESL);
  const int4* col4 = (const int4*)(col + s * CS_ESL);
  _Float16* eo = e_out + (size_t)s * CS_ESL;
  const int n8 = CS_ESL / 8;  // 12500

#define CS_SLOT(r, c, j)                                   \
  do {                                                     \
    int rr = (r)-lo;                                       \
    if ((unsigned)rr < CS_PART) {                          \
      float a = src_lds[rr] + s_dst[(c)];                  \
      a = (a > 0.0f) ? a : NEG_SLOPE * a;                  \
      _Float16 h = (_Float16)__expf(a);                    \
      eo[8 * i + (j)] = h;                                 \
      atomicAdd(&acc[rr], (float)h);                       \
    }                                                      \
  } while (0)

  for (int i = threadIdx.x; i < n8; i += BLK) {
    int4 ra = row4[2 * i], rb = row4[2 * i + 1];
    int4 ca = col4[2 * i], cb = col4[2 * i + 1];
    CS_SLOT(ra.x, ca.x, 0);
    CS_SLOT(ra.y, ca.y, 1);
    CS_SLOT(ra.z, ca.z, 2);
    CS_SLOT(ra.w, ca.w, 3);
    CS_SLOT(rb.x, cb.x, 4);
    CS_SLOT(rb.y, cb.y, 5);
    CS_SLOT(rb.z, cb.z, 6);
    CS_SLOT(rb.w, cb.w, 7);
  }
#undef CS_SLOT
  __syncthreads();
  float* outp = partial + (size_t)s * NN + lo;
  for (int i = threadIdx.x; i < CS_PART; i += BLK) outp[i] = acc[i];
}

// Kernel D: fold 32 slice-partials (float4), store reciprocal.
__global__ __launch_bounds__(256) void reduce_kernel(
    const float* __restrict__ partial,
    float* __restrict__ denom) {
  int n4 = blockIdx.x * blockDim.x + threadIdx.x;
  if (n4 >= NN / 4) return;
  float4 sum = make_float4(0.f, 0.f, 0.f, 0.f);
#pragma unroll 8
  for (int s = 0; s < CS_S; ++s) {
    float4 v = ((const float4*)(partial + (size_t)s * NN))[n4];
    sum.x += v.x; sum.y += v.y; sum.z += v.z; sum.w += v.w;
  }
  ((float4*)denom)[n4] = make_float4(1.f / sum.x, 1.f / sum.y, 1.f / sum.z, 1.f / sum.w);
}

// Kernel E': gather-free normalize. Block (s,p) stages the denom-reciprocal
// partition in LDS (100 KB), streams slice s's row+e, and writes
// out[edge] = e * recip[row] predicated (row in partition). Replaces 25.6M
// random denom[row] L2 gathers with LDS reads + a 4x L2-resident re-stream.
// Sparse out writes merge in the shared per-XCD L2 (siblings same XCD).
__global__ __launch_bounds__(BLK) void norm_kernel(
    const int* __restrict__ row,
    const _Float16* __restrict__ e,
    const float* __restrict__ denom,
    float* __restrict__ out) {
  __shared__ float d_lds[EN_PART];  // 100 KB
  int s  = blockIdx.x;
  int p  = blockIdx.y;
  int lo = p * EN_PART;
  for (int i = threadIdx.x; i < EN_PART; i += BLK) d_lds[i] = denom[lo + i];
  __syncthreads();
  const int4*  row4 = (const int4*)(row + s * EN_ESL);
  const half8* e8   = (const half8*)(e + (size_t)s * EN_ESL);
  float* op = out + (size_t)s * EN_ESL;
  const int n8 = EN_ESL / 8;  // 6250

#define EN_SLOT(r, v, j)                                   \
  do {                                                     \
    int rr = (r)-lo;                                       \
    if ((unsigned)rr < EN_PART)                            \
      op[8 * i + (j)] = (float)(v)*d_lds[rr];              \
  } while (0)

  for (int i = threadIdx.x; i < n8; i += BLK) {
    int4 ra = row4[2 * i], rb = row4[2 * i + 1];
    half8 ev = e8[i];
    EN_SLOT(ra.x, ev[0], 0);
    EN_SLOT(ra.y, ev[1], 1);
    EN_SLOT(ra.z, ev[2], 2);
    EN_SLOT(ra.w, ev[3], 3);
    EN_SLOT(rb.x, ev[4], 4);
    EN_SLOT(rb.y, ev[5], 5);
    EN_SLOT(rb.z, ev[6], 6);
    EN_SLOT(rb.w, ev[7], 7);
  }
#undef EN_SLOT
}

extern "C" void kernel_launch(void* const* d_in, const int* in_sizes, int n_in,
                              void* d_out, int out_size, void* d_ws, size_t ws_size,
                              hipStream_t stream) {
  const float* x   = (const float*)d_in[0];
  const float* att = (const float*)d_in[1];
  const int* ei    = (const int*)d_in[2];  // (2, E): row then col (int32)
  const int* row   = ei;
  const int* col   = ei + NE;
  float* out       = (float*)d_out;  // E floats, final output

  float* s_src    = (float*)d_ws;            // N f32
  float* s_dst    = s_src + NN;              // N f32
  float* denom    = s_dst + NN;              // N f32
  _Float16* e_buf = (_Float16*)(denom + NN); // E f16 (6.4 MB)
  float* partial  = (float*)(e_buf + NE);    // CS_S * N f32 (12.8 MB)

  node_scores_kernel<<<(NN * 16 + 255) / 256, 256, 0, stream>>>(x, att, s_src, s_dst);
  dim3 cs_grid(CS_S, CS_P);
  fused_segsum_kernel<<<cs_grid, BLK, 0, stream>>>(
      row, col, s_src, s_dst, e_buf, partial);
  reduce_kernel<<<(NN / 4 + 255) / 256, 256, 0, stream>>>(partial, denom);
  dim3 en_grid(EN_S, EN_P);
  norm_kernel<<<en_grid, BLK, 0, stream>>>(row, e_buf, denom, out);
}

// Round 4
// 231.801 us; speedup vs baseline: 1.5077x; 1.0041x over previous
//
#include <hip/hip_runtime.h>

#define NN 100000
#define NE 3200000
#define CC 256
#define NEG_SLOPE 0.2f

// Fused exp+segsum: 80 edge slices x 3 node-partition passes = 240 blocks
// (1 per CU; 160 KB LDS forces 1 block/CU anyway).
#define FS_S 80
#define FS_P 3
#define FS_PART 40000        // f32 acc = 160000 B LDS (<= 163840 limit)
#define FS_ESL (NE / FS_S)   // 40000 edges per slice
#define BLK 1024

typedef __attribute__((ext_vector_type(8))) _Float16 half8;

// Kernel A: dual dot product, 16 lanes per node (4 nodes/wave).
// Lane gl loads x[node][16gl .. 16gl+15] (4 consecutive float4 = 64 B/lane).
// Near HBM floor: reads x (102.4 MB) once -> ~17 us.
__global__ __launch_bounds__(256) void node_scores_kernel(
    const float* __restrict__ x,
    const float* __restrict__ att,
    float* __restrict__ s_src,
    float* __restrict__ s_dst) {
  int t    = blockIdx.x * blockDim.x + threadIdx.x;
  int node = t >> 4;
  int gl   = t & 15;
  if (node >= NN) return;
  const float4* xr = (const float4*)(x + (size_t)node * CC) + gl * 4;
  const float4* a0 = (const float4*)att + gl * 4;         // att[:C]
  const float4* a1 = (const float4*)(att + CC) + gl * 4;  // att[C:]
  float s0 = 0.f, s1 = 0.f;
#pragma unroll
  for (int j = 0; j < 4; ++j) {
    float4 xv = xr[j];
    float4 av = a0[j];
    float4 bv = a1[j];
    s0 += xv.x * av.x + xv.y * av.y + xv.z * av.z + xv.w * av.w;
    s1 += xv.x * bv.x + xv.y * bv.y + xv.z * bv.z + xv.w * bv.w;
  }
#pragma unroll
  for (int m = 8; m >= 1; m >>= 1) {
    s0 += __shfl_xor(s0, m, 64);  // masks <16 stay within the 16-lane group
    s1 += __shfl_xor(s1, m, 64);
  }
  if (gl == 0) {
    s_src[node] = s0;
    s_dst[node] = s1;
  }
}

// Kernel C: fused exp + segment-sum, 3 partition passes over each slice.
// Block (s,p): stream slice s's row (unpredicated int4); for rows in
// partition p only: load col (predicated scalar), gather s_src/s_dst
// (predicated; 400 KB tables, L2-resident -> cheap per rounds 2-3 evidence),
// compute leaky+exp, store e (f16, rounded), LDS-atomic-accumulate f32.
// Max-subtraction of softmax cancels algebraically -> no segment-max pass.
// exp(alpha) in [e^-2, e^8]: f16 rel err 5e-4, safe vs 1.55e-2 threshold.
// Grid (FS_S, FS_P): linear id = s + 80p == s (mod 8) -> the 3 sibling
// blocks of a slice share an XCD and run CONCURRENTLY (240 blocks all
// resident) -> passes 2,3 of the idx stream hit that XCD's L2.
__global__ __launch_bounds__(BLK) void fused_segsum_kernel(
    const int* __restrict__ row,
    const int* __restrict__ col,
    const float* __restrict__ s_src,
    const float* __restrict__ s_dst,
    _Float16* __restrict__ e_out,
    float* __restrict__ partial /* [FS_S][NN] */) {
  __shared__ float acc[FS_PART];  // 160000 B
  int s  = blockIdx.x;
  int p  = blockIdx.y;
  int lo = p * FS_PART;
  for (int i = threadIdx.x; i < FS_PART; i += BLK) acc[i] = 0.0f;
  __syncthreads();
  const int4* row4 = (const int4*)(row + s * FS_ESL);
  const int*  cols = col + s * FS_ESL;
  _Float16* eo = e_out + (size_t)s * FS_ESL;
  const int n8 = FS_ESL / 8;  // 5000

#define FS_SLOT(r, j)                                      \
  do {                                                     \
    int rr = (r)-lo;                                       \
    if ((unsigned)rr < FS_PART) {                          \
      float a = s_src[(r)] + s_dst[cols[8 * i + (j)]];     \
      a = (a > 0.0f) ? a : NEG_SLOPE * a;                  \
      _Float16 h = (_Float16)__expf(a);                    \
      eo[8 * i + (j)] = h;                                 \
      atomicAdd(&acc[rr], (float)h);                       \
    }                                                      \
  } while (0)

  for (int i = threadIdx.x; i < n8; i += BLK) {
    int4 ra = row4[2 * i], rb = row4[2 * i + 1];
    FS_SLOT(ra.x, 0);
    FS_SLOT(ra.y, 1);
    FS_SLOT(ra.z, 2);
    FS_SLOT(ra.w, 3);
    FS_SLOT(rb.x, 4);
    FS_SLOT(rb.y, 5);
    FS_SLOT(rb.z, 6);
    FS_SLOT(rb.w, 7);
  }
#undef FS_SLOT
  __syncthreads();
  int cnt = NN - lo;
  if (cnt > FS_PART) cnt = FS_PART;
  float* outp = partial + (size_t)s * NN + lo;
  for (int i = threadIdx.x; i < cnt; i += BLK) outp[i] = acc[i];
}

// Kernel D: fold 80 slice-partials (float4), store reciprocal (32 MB read).
__global__ __launch_bounds__(256) void reduce_kernel(
    const float* __restrict__ partial,
    float* __restrict__ denom) {
  int n4 = blockIdx.x * blockDim.x + threadIdx.x;
  if (n4 >= NN / 4) return;
  float4 sum = make_float4(0.f, 0.f, 0.f, 0.f);
#pragma unroll 8
  for (int s = 0; s < FS_S; ++s) {
    float4 v = ((const float4*)(partial + (size_t)s * NN))[n4];
    sum.x += v.x; sum.y += v.y; sum.z += v.z; sum.w += v.w;
  }
  ((float4*)denom)[n4] = make_float4(1.f / sum.x, 1.f / sum.y, 1.f / sum.z, 1.f / sum.w);
}

// Kernel E: 8 edges/thread, normalize e (fp16) into final fp32 out.
// Direct denom gather (400 KB table, L2-resident; gathers proven cheap).
__global__ __launch_bounds__(256) void edge_div_kernel(
    const int4* __restrict__ row4,
    const half8* __restrict__ e,
    const float* __restrict__ denom,
    float4* __restrict__ out4) {
  int i = blockIdx.x * blockDim.x + threadIdx.x;
  if (i >= NE / 8) return;
  int4 ra = row4[2 * i], rb = row4[2 * i + 1];
  half8 ev = e[i];
  float4 oa, ob;
  oa.x = (float)ev[0] * denom[ra.x];
  oa.y = (float)ev[1] * denom[ra.y];
  oa.z = (float)ev[2] * denom[ra.z];
  oa.w = (float)ev[3] * denom[ra.w];
  ob.x = (float)ev[4] * denom[rb.x];
  ob.y = (float)ev[5] * denom[rb.y];
  ob.z = (float)ev[6] * denom[rb.z];
  ob.w = (float)ev[7] * denom[rb.w];
  out4[2 * i]     = oa;
  out4[2 * i + 1] = ob;
}

extern "C" void kernel_launch(void* const* d_in, const int* in_sizes, int n_in,
                              void* d_out, int out_size, void* d_ws, size_t ws_size,
                              hipStream_t stream) {
  const float* x   = (const float*)d_in[0];
  const float* att = (const float*)d_in[1];
  const int* ei    = (const int*)d_in[2];  // (2, E): row then col (int32)
  const int* row   = ei;
  const int* col   = ei + NE;
  const int4* row4 = (const int4*)ei;
  float4* out4     = (float4*)d_out;  // E floats, final output

  float* s_src    = (float*)d_ws;            // N f32
  float* s_dst    = s_src + NN;              // N f32
  float* denom    = s_dst + NN;              // N f32
  _Float16* e_buf = (_Float16*)(denom + NN); // E f16 (6.4 MB)
  float* partial  = (float*)(e_buf + NE);    // FS_S * N f32 (32 MB)

  node_scores_kernel<<<(NN * 16 + 255) / 256, 256, 0, stream>>>(x, att, s_src, s_dst);
  dim3 fs_grid(FS_S, FS_P);
  fused_segsum_kernel<<<fs_grid, BLK, 0, stream>>>(
      row, col, s_src, s_dst, e_buf, partial);
  reduce_kernel<<<(NN / 4 + 255) / 256, 256, 0, stream>>>(partial, denom);
  edge_div_kernel<<<(NE / 8 + 255) / 256, 256, 0, stream>>>(
      row4, (const half8*)e_buf, denom, out4);
}